// Round 12
// baseline (124.391 us; speedup 1.0000x reference)
//
#include <hip/hip_runtime.h>
#include <hip/hip_fp16.h>
#include <math.h>

#define CC 64
#define KK 16
#define NNODES 15
#define DD 512      // input feature dim
#define MM 512      // output dim
#define NN 16384    // rows

typedef _Float16 half8 __attribute__((ext_vector_type(8)));
typedef float f32x4 __attribute__((ext_vector_type(4)));
typedef unsigned long long u64;

// ---------------------------------------------------------------------------
// XLA/Eigen fast-tanh for f32 (bit-exact vs JAX's jnp.tanh lowering).
// ---------------------------------------------------------------------------
__device__ __forceinline__ float xla_tanhf(float x) {
    const float kMax = 7.90531110763549805f;
    bool tiny = fabsf(x) < 0.0004f;
    float xc = fminf(fmaxf(x, -kMax), kMax);
    float x2 = __fmul_rn(xc, xc);
    float p = __fmaf_rn(x2, -2.76076847742355e-16f, 2.00018790482477e-13f);
    p = __fmaf_rn(x2, p, -8.60467152213735e-11f);
    p = __fmaf_rn(x2, p, 5.12229709037114e-08f);
    p = __fmaf_rn(x2, p, 1.48572235717979e-05f);
    p = __fmaf_rn(x2, p, 6.37261928875436e-04f);
    p = __fmaf_rn(x2, p, 4.89352455891786e-03f);
    p = __fmul_rn(xc, p);
    float q = __fmaf_rn(x2, 1.19825839466702e-06f, 1.18534705686654e-04f);
    q = __fmaf_rn(x2, q, 2.26843463243900e-03f);
    q = __fmaf_rn(x2, q, 4.89352518554385e-03f);
    return tiny ? x : __fdiv_rn(p, q);
}

// ---------------------------------------------------------------------------
// Kernel 1: pack L (M, C, K) fp32 -> Bpk fp16 in MFMA-B fragment order.
// (round-1 verified)
// ---------------------------------------------------------------------------
__global__ __launch_bounds__(256) void pack_bfrag(const float* __restrict__ L,
                                                  uint4* __restrict__ Bpk) {
    const int t    = blockIdx.x * 256 + threadIdx.x;  // 0..65535
    const int lane = t & 63;
    const int mtg  = (t >> 6) & 31;                   // global m-tile 0..31
    const int ks   = t >> 11;                         // k-step 0..31
    const int kbase = ks * 32 + ((lane >> 4) << 3);   // 8-aligned k window
    const int c     = kbase >> 4;                     // subspace
    const int slot0 = kbase & 15;                     // 0 or 8
    const int m     = (mtg << 4) + (lane & 15);

    const float* src = L + ((size_t)m * CC + c) * KK + slot0;
    float4 v0 = ((const float4*)src)[0];
    float4 v1 = ((const float4*)src)[1];
    union { half8 h; uint4 u; } pk;
    pk.h[0] = (_Float16)v0.x; pk.h[1] = (_Float16)v0.y;
    pk.h[2] = (_Float16)v0.z; pk.h[3] = (_Float16)v0.w;
    pk.h[4] = (_Float16)v1.x; pk.h[5] = (_Float16)v1.y;
    pk.h[6] = (_Float16)v1.z; pk.h[7] = (_Float16)v1.w;
    Bpk[t] = pk.u;
}

// ---------------------------------------------------------------------------
// Kernel 2: ENCODE (standalone, unchanged from round 5 — clean counters).
// ---------------------------------------------------------------------------
__global__ __launch_bounds__(256, 4) void encode_kernel(const float* __restrict__ I,
                                                        const float* __restrict__ A,
                                                        const float* __restrict__ T,
                                                        unsigned* __restrict__ codesG) {
    __shared__ float sA[32 * 64];              // TRANSPOSED: [s*4+d][c]
    __shared__ float sT[CC * NNODES];

    const int tid = threadIdx.x;
    for (int i = tid; i < CC * 32; i += 256) sA[(i & 31) * 64 + (i >> 5)] = A[i];
    for (int i = tid; i < CC * NNODES; i += 256) sT[i] = T[i];
    __syncthreads();

    const int lane = tid & 63;
    const int c    = lane;
    const int w    = ((blockIdx.x & 3) << 2) + (tid >> 6);   // 0..15
    const int tile = blockIdx.x >> 2;
    const int n0   = tile * 64;

    float a_[32];
#pragma unroll
    for (int i = 0; i < 32; ++i) a_[i] = sA[i * 64 + c];
    float tt[NNODES];
#pragma unroll
    for (int i = 0; i < NNODES; ++i) tt[i] = sT[c * NNODES + i];

    const int lvl[NNODES] = {0, 1, 1, 2, 2, 2, 2, 3, 3, 3, 3, 3, 3, 3, 3};
    unsigned codeWord = 0;
#pragma unroll 2
    for (int rr = 0; rr < 4; ++rr) {
        const int rl = (rr << 4) + w;
        const float* Ij = I + (size_t)(n0 + rl) * DD + c * 8;
        float4 v0 = ((const float4*)Ij)[0];
        float4 v1 = ((const float4*)Ij)[1];
        float iv[8] = {v0.x, v0.y, v0.z, v0.w, v1.x, v1.y, v1.z, v1.w};

        float t[4] = {0.f, 0.f, 0.f, 0.f};
#pragma unroll
        for (int s = 0; s < 8; ++s) {
            float v = iv[s];
#pragma unroll
            for (int d = 0; d < 4; ++d)
                t[d] = __fmaf_rn(v, a_[(s << 2) + d], t[d]);
        }

        float th[NNODES];
#pragma unroll
        for (int i = 0; i < NNODES; ++i) {
            float h = __fsub_rn(t[lvl[i]], tt[i]);
            th[i] = xla_tanhf(h);
        }

        int best = 0;
        float bestv = -3.0e38f;
#pragma unroll
        for (int k = 0; k < KK; ++k) {
            int node = 0;
            float s = 0.f;
#pragma unroll
            for (int l = 0; l < 4; ++l) {
                int bit = (k >> (3 - l)) & 1;
                s = __fadd_rn(s, bit ? th[node] : -th[node]);
                node = 2 * node + 1 + bit;
            }
            if (s > bestv) { bestv = s; best = k; }   // strict >: first-max
        }
        codeWord |= ((unsigned)best) << (rr << 3);
    }
    codesG[(size_t)tile * 1024 + (w << 6) + c] = codeWord;
}

// ---------------------------------------------------------------------------
// Kernel 3: DECODE v4 — register-staged, barrier-free, EIGHT k-steps deep.
// R11 evidence: v3 (4-deep) decode ~24us vs 9-10us steady-state model ->
// ~14us exposed load latency (first-touch HBM ~900cy on Bpk, convoyed
// vmcnt waits). TLP is VGPR-capped at 2 waves/SIMD, so the lever is ILP:
// depth 4 -> 8 named sets (rule-#20 safe). Cover = 7 x ~440cy ~ 3100cy >
// cold-HBM latency. 40 loads in flight/wave < vmcnt max 63. VGPR ~230 <
// 256 cap at (256,2). Spill tripwire: decode FETCH >> 3MB. If NEUTRAL ->
// issue-bound -> next: one-hot VALU cut or s_setprio around MFMA (T5).
// Set G's code word is named cQ (pointer cG already taken).
// ---------------------------------------------------------------------------
#define LOADSET(S, ks_)                              \
    b##S##0 = Bp[((ks_) * 32 + 0) * 64];             \
    b##S##1 = Bp[((ks_) * 32 + 1) * 64];             \
    b##S##2 = Bp[((ks_) * 32 + 2) * 64];             \
    b##S##3 = Bp[((ks_) * 32 + 3) * 64];             \
    cw##S = cG[(ks_) << 1];

#define COMPUTESET(S) do {                                                        \
    const unsigned cw = cw##S;                                                    \
    half8 a_[4];                                                                  \
    _Pragma("unroll")                                                             \
    for (int nt = 0; nt < 4; ++nt) {                                              \
        unsigned ud  = ((cw >> (nt << 3)) & 255u) - (unsigned)sb;                 \
        unsigned ud2 = ud - 4u;                                                   \
        u64 lo = (ud  < 4u) ? (0x3C00ull << ((ud  & 3u) << 4)) : 0ull;            \
        u64 hi = (ud2 < 4u) ? (0x3C00ull << ((ud2 & 3u) << 4)) : 0ull;            \
        union { u64 q[2]; half8 h; } uu; uu.q[0] = lo; uu.q[1] = hi;              \
        a_[nt] = uu.h;                                                            \
    }                                                                             \
    union { uint4 u; half8 h; } q0, q1, q2, q3;                                   \
    q0.u = b##S##0; q1.u = b##S##1; q2.u = b##S##2; q3.u = b##S##3;               \
    _Pragma("unroll")                                                             \
    for (int nt = 0; nt < 4; ++nt) {                                              \
        acc[nt][0] = __builtin_amdgcn_mfma_f32_16x16x32_f16(a_[nt], q0.h, acc[nt][0], 0, 0, 0); \
        acc[nt][1] = __builtin_amdgcn_mfma_f32_16x16x32_f16(a_[nt], q1.h, acc[nt][1], 0, 0, 0); \
        acc[nt][2] = __builtin_amdgcn_mfma_f32_16x16x32_f16(a_[nt], q2.h, acc[nt][2], 0, 0, 0); \
        acc[nt][3] = __builtin_amdgcn_mfma_f32_16x16x32_f16(a_[nt], q3.h, acc[nt][3], 0, 0, 0); \
    }                                                                             \
} while (0)

__global__ __launch_bounds__(256, 2) void decode_kernel(const unsigned* __restrict__ codesG,
                                                        const uint4* __restrict__ Bpk,
                                                        float* __restrict__ out) {
    const int tid = threadIdx.x;
    const int bn  = blockIdx.x >> 2;        // 0..127 (128-row group)
    const int bm  = blockIdx.x & 3;         // 0..3   (128-col strip)
    const int n0  = bn << 7;
    const int m0  = bm << 7;

    const int w    = tid >> 6;              // wave 0..3
    const int lane = tid & 63;
    const int wn   = w >> 1;                // row half (64 rows = one code tile)
    const int wm   = w & 1;                 // col half (64 cols = 4 m-tiles)
    const int r15  = lane & 15;
    const int sb   = ((lane >> 4) & 1) << 3;
    const int chi  = lane >> 5;

    // per-lane bases: B frag (ks,j) at Bp[(ks*32 + j)*64]; code word at cG[2ks]
    const uint4* Bp = Bpk + ((bm << 3) + (wm << 2)) * 64 + lane;
    const unsigned* cG = codesG + ((size_t)((bn << 1) | wn) << 10) + (r15 << 6) + chi;

    f32x4 acc[4][4];
#pragma unroll
    for (int nt = 0; nt < 4; ++nt)
#pragma unroll
        for (int mt = 0; mt < 4; ++mt)
            acc[nt][mt] = (f32x4){0.f, 0.f, 0.f, 0.f};

    uint4 bA0, bA1, bA2, bA3; unsigned cwA;
    uint4 bB0, bB1, bB2, bB3; unsigned cwB;
    uint4 bC0, bC1, bC2, bC3; unsigned cwC;
    uint4 bD0, bD1, bD2, bD3; unsigned cwD;
    uint4 bE0, bE1, bE2, bE3; unsigned cwE;
    uint4 bF0, bF1, bF2, bF3; unsigned cwF;
    uint4 bG0, bG1, bG2, bG3; unsigned cwG;
    uint4 bH0, bH1, bH2, bH3; unsigned cwH;

    // prologue: 8 k-steps in flight (40 outstanding loads < vmcnt max 63)
    LOADSET(A, 0)
    LOADSET(B, 1)
    LOADSET(C, 2)
    LOADSET(D, 3)
    LOADSET(E, 4)
    LOADSET(F, 5)
    LOADSET(G, 6)
    LOADSET(H, 7)

#pragma unroll 1
    for (int g = 0; g < 4; ++g) {
        const int ks = g << 3;
        const bool more = g < 3;
        COMPUTESET(A); if (more) { LOADSET(A, ks + 8) }
        COMPUTESET(B); if (more) { LOADSET(B, ks + 9) }
        COMPUTESET(C); if (more) { LOADSET(C, ks + 10) }
        COMPUTESET(D); if (more) { LOADSET(D, ks + 11) }
        COMPUTESET(E); if (more) { LOADSET(E, ks + 12) }
        COMPUTESET(F); if (more) { LOADSET(F, ks + 13) }
        COMPUTESET(G); if (more) { LOADSET(G, ks + 14) }
        COMPUTESET(H); if (more) { LOADSET(H, ks + 15) }
    }

    // ---- epilogue: D layout col=lane&15, row=(lane>>4)*4+reg ----
    const int rbase = (lane >> 4) << 2;
#pragma unroll
    for (int nt = 0; nt < 4; ++nt) {
#pragma unroll
        for (int r = 0; r < 4; ++r) {
            float* o = out + (size_t)(n0 + ((wn << 2) + nt) * 16 + rbase + r) * MM
                           + m0 + (wm << 6) + r15;
#pragma unroll
            for (int mt = 0; mt < 4; ++mt)
                o[mt << 4] = acc[nt][mt][r];
        }
    }
}

// ---------------------------------------------------------------------------
extern "C" void kernel_launch(void* const* d_in, const int* in_sizes, int n_in,
                              void* d_out, int out_size, void* d_ws, size_t ws_size,
                              hipStream_t stream) {
    const float* I = (const float*)d_in[0];  // (N, D) fp32
    const float* A = (const float*)d_in[1];  // (C, 8, 4) fp32
    const float* T = (const float*)d_in[2];  // (C*15,) fp32
    const float* L = (const float*)d_in[3];  // (M, C, K) fp32
    // d_in[4] = S, d_in[5] = B: structural constants, hard-coded.

    uint4* Bpk = (uint4*)d_ws;                               // 1 MB fp16 LUT frags
    unsigned* codesG = (unsigned*)((char*)d_ws + (1 << 20)); // 1 MB packed codes
    float* out = (float*)d_out;                              // (N, M) fp32

    hipLaunchKernelGGL(pack_bfrag, dim3(256), dim3(256), 0, stream, L, Bpk);
    hipLaunchKernelGGL(encode_kernel, dim3(1024), dim3(256), 0, stream, I, A, T, codesG);
    hipLaunchKernelGGL(decode_kernel, dim3(512), dim3(256), 0, stream, codesG, Bpk, out);
}